// Round 1
// baseline (497.230 us; speedup 1.0000x reference)
//
#include <hip/hip_runtime.h>

#define BCNT 16
#define TT 1024
#define DIN 384
#define H1 1024
#define H2 1024
#define KW 9

typedef __attribute__((ext_vector_type(8))) short bhalf8;   // 8 bf16 in 4 VGPRs
typedef __attribute__((ext_vector_type(4))) float f32x4;

__device__ __forceinline__ float bf2f(unsigned short u) {
    return __uint_as_float(((unsigned int)u) << 16);
}
__device__ __forceinline__ unsigned short f2bf(float f) {
    unsigned int u = __float_as_uint(f);
    unsigned int r = (u + 0x7FFFu + ((u >> 16) & 1u)) >> 16;  // RNE
    return (unsigned short)r;
}
__device__ __forceinline__ float mish_f(float x) {
    float sp = (x > 20.f) ? x : log1pf(expf(x));
    return x * tanhf(sp);
}

// ---------------- small prep kernels ----------------

// norm over channels for each (b, k) tap of d_w (B,H1,1,K)
__global__ void k_norm_d(const float* __restrict__ d_w, float* __restrict__ norm_d) {
    int idx = blockIdx.x;           // b*KW + k
    int b = idx / KW, k = idx % KW;
    float s = 0.f;
    for (int c = threadIdx.x; c < H1; c += 256) {
        float v = d_w[((size_t)b * H1 + c) * KW + k];
        s += v * v;
    }
    __shared__ float red[256];
    red[threadIdx.x] = s; __syncthreads();
    for (int st = 128; st > 0; st >>= 1) {
        if (threadIdx.x < st) red[threadIdx.x] += red[threadIdx.x + st];
        __syncthreads();
    }
    if (threadIdx.x == 0) norm_d[idx] = sqrtf(red[0]);
}

// dwn_s[b,c,k] = d_w[b,c,0,k] / max(norm_d[b,k],1e-12) * d_g[b,c] * T
__global__ void k_dwn(const float* __restrict__ d_w, const float* __restrict__ d_g,
                      const float* __restrict__ norm_d, float* __restrict__ dwn_s) {
    int i = blockIdx.x * 256 + threadIdx.x;  // < B*H1*KW (exact)
    int k = i % KW;
    int c = (i / KW) % H1;
    int b = i / (KW * H1);
    float n = fmaxf(norm_d[b * KW + k], 1e-12f);
    dwn_s[i] = d_w[i] / n * d_g[b * H1 + c] * (float)TT;
}

// inv_np[b,o] = 1/max(||p_w[b,:,o]||,1e-12)
__global__ __launch_bounds__(256) void k_norm_p(const float* __restrict__ p_w,
                                                float* __restrict__ inv_np) {
    int o = blockIdx.y * 256 + threadIdx.x;
    int b = blockIdx.x;
    float s = 0.f;
    for (int c = 0; c < H1; c++) {
        float v = p_w[((size_t)b * H1 + c) * H2 + o];
        s += v * v;
    }
    inv_np[b * H2 + o] = 1.0f / fmaxf(sqrtf(s), 1e-12f);
}

// pwT[b,o,c] = bf16( p_w[b,c,o] * inv_np[b,o] * p_g[b,c] )
__global__ __launch_bounds__(256) void k_tpw(const float* __restrict__ p_w,
                                             const float* __restrict__ inv_np,
                                             const float* __restrict__ p_g,
                                             unsigned short* __restrict__ pwT) {
    __shared__ float tile[32][33];
    int tx = threadIdx.x & 31, ty = threadIdx.x >> 5;  // 32 x 8
    int c0 = blockIdx.x * 32, o0 = blockIdx.y * 32, b = blockIdx.z;
#pragma unroll
    for (int j = 0; j < 4; j++)
        tile[ty + j * 8][tx] = p_w[((size_t)b * H1 + c0 + ty + j * 8) * H2 + o0 + tx];
    __syncthreads();
#pragma unroll
    for (int j = 0; j < 4; j++) {
        int o = o0 + ty + j * 8, c = c0 + tx;
        float v = tile[tx][ty + j * 8] * inv_np[b * H2 + o] * p_g[(size_t)b * H1 + c];
        pwT[((size_t)b * H2 + o) * H1 + c] = f2bf(v);
    }
}

// depthwise conv along T, sliding window: y[b,t,c] = sum_k h[b,t-4+k,c]*dwn_s[b,c,k] + d_b[b,c]
__global__ __launch_bounds__(256) void k_conv(const unsigned short* __restrict__ h,
                                              const float* __restrict__ dwn_s,
                                              const float* __restrict__ d_b,
                                              unsigned short* __restrict__ y) {
    int tid = threadIdx.x;
    int c = blockIdx.y * 256 + tid;
    int t0 = blockIdx.x * 128;
    int b = blockIdx.z;
    const unsigned short* hb = h + (size_t)b * TT * H1;
    float ker[KW];
#pragma unroll
    for (int i = 0; i < KW; i++) ker[i] = dwn_s[((size_t)b * H1 + c) * KW + i];
    float db = d_b[b * H1 + c];
    float w[KW];
#pragma unroll
    for (int i = 0; i < 8; i++) {
        int t = t0 - 4 + i;
        w[i] = (t >= 0 && t < TT) ? bf2f(hb[(size_t)t * H1 + c]) : 0.f;
    }
    for (int j = 0; j < 128; j++) {
        int t = t0 + j;
        int tl = t + 4;
        w[8] = (tl < TT) ? bf2f(hb[(size_t)tl * H1 + c]) : 0.f;
        float acc = db;
#pragma unroll
        for (int i = 0; i < KW; i++) acc += ker[i] * w[i];
        y[((size_t)b * TT + t) * H1 + c] = f2bf(acc);
#pragma unroll
        for (int i = 0; i < 8; i++) w[i] = w[i + 1];
    }
}

// ---------------- templated NT bf16 MFMA GEMM ----------------
// C[m,n] = sum_k A[m,k] * B[n,k]  (both K-contiguous), 128x128 tile, BK=32.
// MODE 0: C=bf16( mish(v + bias[n]) )          (G1)
// MODE 1: C=bf16( v + bias[bz*biasStride+n] )  (G2, per-batch bias)
// MODE 2: C=f32 ( v + bias[n] + resid[idx] )   (G3, residual add)
#define LDSK 40  // padded row stride (bf16 elems): 80B rows, conflict-free b128 reads

template <bool AF32, bool BF32, int MODE>
__global__ __launch_bounds__(256) void gemm_nt(
    const void* __restrict__ Ap, const void* __restrict__ Bp, void* __restrict__ Cp,
    int Kdim, int lda, int ldb, int ldc,
    long sA, long sB, long sC,
    const float* __restrict__ bias, int biasStride,
    const float* __restrict__ resid) {
    __shared__ __attribute__((aligned(16))) unsigned short Al[128 * LDSK];
    __shared__ __attribute__((aligned(16))) unsigned short Bl[128 * LDSK];

    const int tid = threadIdx.x;
    const int bm = blockIdx.x * 128, bn = blockIdx.y * 128, bz = blockIdx.z;

    const char* Abase = (const char*)Ap + (size_t)sA * bz * (AF32 ? 4 : 2);
    const char* Bbase = (const char*)Bp + (size_t)sB * bz * (BF32 ? 4 : 2);

    const int r0 = tid >> 3;         // 0..31
    const int kq = (tid & 7) * 4;    // 0,4,...,28

    const int lane = tid & 63, wv = tid >> 6;
    const int wm = (wv >> 1) * 64, wn = (wv & 1) * 64;
    const int l16 = lane & 15, quad = lane >> 4;

    f32x4 acc[4][4];
#pragma unroll
    for (int i = 0; i < 4; i++)
#pragma unroll
        for (int j = 0; j < 4; j++)
#pragma unroll
            for (int r = 0; r < 4; r++) acc[i][j][r] = 0.f;

    const int ktiles = Kdim / 32;
    for (int kt = 0; kt < ktiles; ++kt) {
        // stage A tile (128 x 32)
#pragma unroll
        for (int p = 0; p < 4; p++) {
            int row = r0 + p * 32;
            if constexpr (AF32) {
                const float4* src =
                    (const float4*)((const float*)Abase + (size_t)(bm + row) * lda + kt * 32 + kq);
                float4 v = *src;
                ushort4 o;
                o.x = f2bf(v.x); o.y = f2bf(v.y); o.z = f2bf(v.z); o.w = f2bf(v.w);
                *(ushort4*)&Al[row * LDSK + kq] = o;
            } else {
                ushort4 v = *(const ushort4*)((const unsigned short*)Abase +
                                              (size_t)(bm + row) * lda + kt * 32 + kq);
                *(ushort4*)&Al[row * LDSK + kq] = v;
            }
        }
        // stage B tile (128 x 32)
#pragma unroll
        for (int p = 0; p < 4; p++) {
            int row = r0 + p * 32;
            if constexpr (BF32) {
                const float4* src =
                    (const float4*)((const float*)Bbase + (size_t)(bn + row) * ldb + kt * 32 + kq);
                float4 v = *src;
                ushort4 o;
                o.x = f2bf(v.x); o.y = f2bf(v.y); o.z = f2bf(v.z); o.w = f2bf(v.w);
                *(ushort4*)&Bl[row * LDSK + kq] = o;
            } else {
                ushort4 v = *(const ushort4*)((const unsigned short*)Bbase +
                                              (size_t)(bn + row) * ldb + kt * 32 + kq);
                *(ushort4*)&Bl[row * LDSK + kq] = v;
            }
        }
        __syncthreads();

        bhalf8 af[4], bf[4];
#pragma unroll
        for (int mi = 0; mi < 4; mi++)
            af[mi] = *(const bhalf8*)&Al[(wm + mi * 16 + l16) * LDSK + quad * 8];
#pragma unroll
        for (int ni = 0; ni < 4; ni++)
            bf[ni] = *(const bhalf8*)&Bl[(wn + ni * 16 + l16) * LDSK + quad * 8];
#pragma unroll
        for (int mi = 0; mi < 4; mi++)
#pragma unroll
            for (int ni = 0; ni < 4; ni++)
                acc[mi][ni] = __builtin_amdgcn_mfma_f32_16x16x32_bf16(af[mi], bf[ni],
                                                                     acc[mi][ni], 0, 0, 0);
        __syncthreads();
    }

    // epilogue: D row = quad*4+r, col = lane&15
#pragma unroll
    for (int mi = 0; mi < 4; mi++)
#pragma unroll
        for (int ni = 0; ni < 4; ni++)
#pragma unroll
            for (int r = 0; r < 4; r++) {
                int gm = bm + wm + mi * 16 + quad * 4 + r;
                int gn = bn + wn + ni * 16 + l16;
                float v = acc[mi][ni][r];
                size_t cidx = (size_t)sC * bz + (size_t)gm * ldc + gn;
                if constexpr (MODE == 0) {
                    v = mish_f(v + bias[gn]);
                    ((unsigned short*)Cp)[cidx] = f2bf(v);
                } else if constexpr (MODE == 1) {
                    v += bias[(size_t)bz * biasStride + gn];
                    ((unsigned short*)Cp)[cidx] = f2bf(v);
                } else {
                    v += bias[gn] + resid[cidx];
                    ((float*)Cp)[cidx] = v;
                }
            }
}

// ---------------- launch ----------------

extern "C" void kernel_launch(void* const* d_in, const int* in_sizes, int n_in,
                              void* d_out, int out_size, void* d_ws, size_t ws_size,
                              hipStream_t stream) {
    const float* input = (const float*)d_in[0];
    const float* d_w   = (const float*)d_in[1];
    const float* d_g   = (const float*)d_in[2];
    const float* d_b   = (const float*)d_in[3];
    const float* p_w   = (const float*)d_in[4];
    const float* p_g   = (const float*)d_in[5];
    const float* p_b   = (const float*)d_in[6];
    const float* w1_w  = (const float*)d_in[7];
    const float* w1_b  = (const float*)d_in[8];
    const float* w2_w  = (const float*)d_in[9];
    const float* w2_b  = (const float*)d_in[10];
    float* out = (float*)d_out;

    char* ws = (char*)d_ws;
    size_t off = 0;
    auto alloc = [&](size_t bytes) {
        char* p = ws + off;
        off += (bytes + 255) & ~(size_t)255;
        return p;
    };
    float* norm_d        = (float*)alloc((size_t)BCNT * KW * 4);
    float* dwn_s         = (float*)alloc((size_t)BCNT * H1 * KW * 4);
    float* inv_np        = (float*)alloc((size_t)BCNT * H2 * 4);
    unsigned short* h    = (unsigned short*)alloc((size_t)BCNT * TT * H1 * 2);
    unsigned short* y    = (unsigned short*)alloc((size_t)BCNT * TT * H1 * 2);
    unsigned short* pwT  = (unsigned short*)alloc((size_t)BCNT * H2 * H1 * 2);
    unsigned short* zt   = (unsigned short*)alloc((size_t)BCNT * TT * H2 * 2);

    // prep
    k_norm_d<<<BCNT * KW, 256, 0, stream>>>(d_w, norm_d);
    k_dwn<<<(BCNT * H1 * KW) / 256, 256, 0, stream>>>(d_w, d_g, norm_d, dwn_s);
    k_norm_p<<<dim3(BCNT, H2 / 256), 256, 0, stream>>>(p_w, inv_np);
    k_tpw<<<dim3(H1 / 32, H2 / 32, BCNT), 256, 0, stream>>>(p_w, inv_np, p_g, pwT);

    // G1: h = bf16(mish(input @ w1_w^T + w1_b)), shape (B*T, H1)
    gemm_nt<true, true, 0><<<dim3(BCNT * TT / 128, H1 / 128, 1), 256, 0, stream>>>(
        input, w1_w, h, DIN, DIN, DIN, H1, 0, 0, 0, w1_b, 0, nullptr);

    // depthwise conv -> y (B*T, H1) bf16
    k_conv<<<dim3(TT / 128, H1 / 256, BCNT), 256, 0, stream>>>(h, dwn_s, d_b, y);

    // G2 (batched): zt[b,t,o] = sum_c y[b,t,c]*pwT[b,o,c] + p_b[b,o]
    gemm_nt<false, false, 1><<<dim3(TT / 128, H2 / 128, BCNT), 256, 0, stream>>>(
        y, pwT, zt, H1, H1, H1, H2, (long)TT * H1, (long)H2 * H1, (long)TT * H2, p_b, H2, nullptr);

    // G3: out[b,t,d] = sum_o zt[b,t,o]*w2_w[d,o] + w2_b[d] + input
    gemm_nt<false, true, 2><<<dim3(BCNT * TT / 128, DIN / 128, 1), 256, 0, stream>>>(
        zt, w2_w, out, H2, H2, H2, DIN, 0, 0, 0, w2_b, 0, input);
}

// Round 2
// 359.826 us; speedup vs baseline: 1.3819x; 1.3819x over previous
//
#include <hip/hip_runtime.h>

#define BCNT 16
#define TT 1024
#define DIN 384
#define H1 1024
#define H2 1024
#define KW 9

typedef __attribute__((ext_vector_type(8))) short bhalf8;   // 8 bf16 in 4 VGPRs
typedef __attribute__((ext_vector_type(4))) float f32x4;

typedef const __attribute__((address_space(1))) void* gas_ptr;
typedef __attribute__((address_space(3))) void* lds_ptr;

__device__ __forceinline__ float bf2f(unsigned short u) {
    return __uint_as_float(((unsigned int)u) << 16);
}
__device__ __forceinline__ unsigned short f2bf(float f) {
    unsigned int u = __float_as_uint(f);
    unsigned int r = (u + 0x7FFFu + ((u >> 16) & 1u)) >> 16;  // RNE
    return (unsigned short)r;
}
// mish(x) = x*tanh(log1p(e^x)) = x*(u^2+2u)/(u^2+2u+2), u=e^x  (exact algebra)
__device__ __forceinline__ float mish_f(float x) {
    if (x > 20.f) return x;           // tanh(softplus) == 1 to fp32 precision
    float u = __expf(x);
    float n = u * u + 2.f * u;
    return x * n / (n + 2.f);
}

// ---------------- prep kernels ----------------

// f32 -> bf16 cvt, vectorized x4
__global__ __launch_bounds__(256) void k_cvt(const float* __restrict__ src,
                                             unsigned short* __restrict__ dst, int n4) {
    int i = blockIdx.x * 256 + threadIdx.x;
    if (i < n4) {
        float4 v = ((const float4*)src)[i];
        ushort4 o;
        o.x = f2bf(v.x); o.y = f2bf(v.y); o.z = f2bf(v.z); o.w = f2bf(v.w);
        ((ushort4*)dst)[i] = o;
    }
}

// norm over channels for each (b, k) tap of d_w (B,H1,1,K)
__global__ void k_norm_d(const float* __restrict__ d_w, float* __restrict__ norm_d) {
    int idx = blockIdx.x;           // b*KW + k
    int b = idx / KW, k = idx % KW;
    float s = 0.f;
    for (int c = threadIdx.x; c < H1; c += 256) {
        float v = d_w[((size_t)b * H1 + c) * KW + k];
        s += v * v;
    }
    __shared__ float red[256];
    red[threadIdx.x] = s; __syncthreads();
    for (int st = 128; st > 0; st >>= 1) {
        if (threadIdx.x < st) red[threadIdx.x] += red[threadIdx.x + st];
        __syncthreads();
    }
    if (threadIdx.x == 0) norm_d[idx] = sqrtf(red[0]);
}

// dwn_s[b,c,k] = d_w[b,c,0,k] / max(norm_d[b,k],1e-12) * d_g[b,c] * T
__global__ void k_dwn(const float* __restrict__ d_w, const float* __restrict__ d_g,
                      const float* __restrict__ norm_d, float* __restrict__ dwn_s) {
    int i = blockIdx.x * 256 + threadIdx.x;  // < B*H1*KW (exact)
    int k = i % KW;
    int c = (i / KW) % H1;
    int b = i / (KW * H1);
    float n = fmaxf(norm_d[b * KW + k], 1e-12f);
    dwn_s[i] = d_w[i] / n * d_g[b * H1 + c] * (float)TT;
}

// partial sums of p_w[b,:,o]^2 over c-chunks of 128 (8 chunks)
__global__ __launch_bounds__(256) void k_norm_p_part(const float* __restrict__ p_w,
                                                     float* __restrict__ part) {
    int o = blockIdx.y * 256 + threadIdx.x;
    int b = blockIdx.x, ch = blockIdx.z;
    float s = 0.f;
    for (int c = ch * 128; c < ch * 128 + 128; c++) {
        float v = p_w[((size_t)b * H1 + c) * H2 + o];
        s += v * v;
    }
    part[((size_t)(b * 8 + ch)) * H2 + o] = s;
}

__global__ __launch_bounds__(256) void k_norm_p_fin(const float* __restrict__ part,
                                                    float* __restrict__ inv_np) {
    int o = blockIdx.y * 256 + threadIdx.x;
    int b = blockIdx.x;
    float s = 0.f;
#pragma unroll
    for (int ch = 0; ch < 8; ch++) s += part[((size_t)(b * 8 + ch)) * H2 + o];
    inv_np[b * H2 + o] = 1.0f / fmaxf(sqrtf(s), 1e-12f);
}

// pwT[b,o,c] = bf16( p_w[b,c,o] * inv_np[b,o] * p_g[b,c] )
__global__ __launch_bounds__(256) void k_tpw(const float* __restrict__ p_w,
                                             const float* __restrict__ inv_np,
                                             const float* __restrict__ p_g,
                                             unsigned short* __restrict__ pwT) {
    __shared__ float tile[32][33];
    int tx = threadIdx.x & 31, ty = threadIdx.x >> 5;  // 32 x 8
    int c0 = blockIdx.x * 32, o0 = blockIdx.y * 32, b = blockIdx.z;
#pragma unroll
    for (int j = 0; j < 4; j++)
        tile[ty + j * 8][tx] = p_w[((size_t)b * H1 + c0 + ty + j * 8) * H2 + o0 + tx];
    __syncthreads();
#pragma unroll
    for (int j = 0; j < 4; j++) {
        int o = o0 + ty + j * 8, c = c0 + tx;
        float v = tile[tx][ty + j * 8] * inv_np[b * H2 + o] * p_g[(size_t)b * H1 + c];
        pwT[((size_t)b * H2 + o) * H1 + c] = f2bf(v);
    }
}

// depthwise conv along T, sliding window
__global__ __launch_bounds__(256) void k_conv(const unsigned short* __restrict__ h,
                                              const float* __restrict__ dwn_s,
                                              const float* __restrict__ d_b,
                                              unsigned short* __restrict__ y) {
    int tid = threadIdx.x;
    int c = blockIdx.y * 256 + tid;
    int t0 = blockIdx.x * 128;
    int b = blockIdx.z;
    const unsigned short* hb = h + (size_t)b * TT * H1;
    float ker[KW];
#pragma unroll
    for (int i = 0; i < KW; i++) ker[i] = dwn_s[((size_t)b * H1 + c) * KW + i];
    float db = d_b[b * H1 + c];
    float w[KW];
#pragma unroll
    for (int i = 0; i < 8; i++) {
        int t = t0 - 4 + i;
        w[i] = (t >= 0 && t < TT) ? bf2f(hb[(size_t)t * H1 + c]) : 0.f;
    }
    for (int j = 0; j < 128; j++) {
        int t = t0 + j;
        int tl = t + 4;
        w[8] = (tl < TT) ? bf2f(hb[(size_t)tl * H1 + c]) : 0.f;
        float acc = db;
#pragma unroll
        for (int i = 0; i < KW; i++) acc += ker[i] * w[i];
        y[((size_t)b * TT + t) * H1 + c] = f2bf(acc);
#pragma unroll
        for (int i = 0; i < 8; i++) w[i] = w[i + 1];
    }
}

// ---------------- bf16 NT MFMA GEMM, m97 structure ----------------
// C[m,n] = sum_k A[m,k]*B[n,k], both bf16 K-contiguous. 128x128 tile, BK=32.
// Staging via global_load_lds width-16: LDS rows are 32 bf16 = 64B, unpadded
// (layout forced by wave-uniform-base + lane*16 rule).
// MODE 0: C=bf16(mish(v + bias[n]))
// MODE 1: C=bf16(v + bias[bz*biasStride+n])
// MODE 2: C=f32 (v + bias[n] + resid[idx])
template <int MODE>
__global__ __launch_bounds__(256) void gemm_nt(
    const unsigned short* __restrict__ A, const unsigned short* __restrict__ Bm,
    void* __restrict__ Cp, int Kdim, int lda, int ldb, int ldc,
    long sA, long sB, long sC,
    const float* __restrict__ bias, int biasStride,
    const float* __restrict__ resid) {
    __shared__ __attribute__((aligned(16))) unsigned short Al[128 * 32];
    __shared__ __attribute__((aligned(16))) unsigned short Bl[128 * 32];

    const int tid = threadIdx.x;
    const int lane = tid & 63, wv = tid >> 6;
    const int bm = blockIdx.x * 128, bn = blockIdx.y * 128, bz = blockIdx.z;

    const unsigned short* Ab = A + (size_t)sA * bz;
    const unsigned short* Bb = Bm + (size_t)sB * bz;

    // staging lane map: chunk = 16 rows; lane covers (row = lane/4, col = (lane&3)*8 elems)
    const int rS = lane >> 2;
    const int cS = (lane & 3) * 8;

    const int wm = (wv >> 1) * 64, wn = (wv & 1) * 64;
    const int l16 = lane & 15, quad = lane >> 4;

    f32x4 acc[4][4];
#pragma unroll
    for (int i = 0; i < 4; i++)
#pragma unroll
        for (int j = 0; j < 4; j++)
#pragma unroll
            for (int r = 0; r < 4; r++) acc[i][j][r] = 0.f;

    const int ktiles = Kdim / 32;
    for (int kt = 0; kt < ktiles; ++kt) {
        const int kofs = kt * 32 + cS;
#pragma unroll
        for (int i = 0; i < 2; i++) {
            const int ch = wv + i * 4;              // 8 chunks of 16 rows
            const unsigned short* ga = Ab + (size_t)(bm + ch * 16 + rS) * lda + kofs;
            __builtin_amdgcn_global_load_lds((gas_ptr)ga, (lds_ptr)&Al[ch * 512], 16, 0, 0);
            const unsigned short* gb = Bb + (size_t)(bn + ch * 16 + rS) * ldb + kofs;
            __builtin_amdgcn_global_load_lds((gas_ptr)gb, (lds_ptr)&Bl[ch * 512], 16, 0, 0);
        }
        __syncthreads();

        bhalf8 af[4], bf[4];
#pragma unroll
        for (int mi = 0; mi < 4; mi++)
            af[mi] = *(const bhalf8*)&Al[(wm + mi * 16 + l16) * 32 + quad * 8];
#pragma unroll
        for (int ni = 0; ni < 4; ni++)
            bf[ni] = *(const bhalf8*)&Bl[(wn + ni * 16 + l16) * 32 + quad * 8];
#pragma unroll
        for (int mi = 0; mi < 4; mi++)
#pragma unroll
            for (int ni = 0; ni < 4; ni++)
                acc[mi][ni] = __builtin_amdgcn_mfma_f32_16x16x32_bf16(af[mi], bf[ni],
                                                                     acc[mi][ni], 0, 0, 0);
        __syncthreads();
    }

    // epilogue: D row = quad*4+r, col = lane&15
#pragma unroll
    for (int mi = 0; mi < 4; mi++)
#pragma unroll
        for (int ni = 0; ni < 4; ni++)
#pragma unroll
            for (int r = 0; r < 4; r++) {
                int gm = bm + wm + mi * 16 + quad * 4 + r;
                int gn = bn + wn + ni * 16 + l16;
                float v = acc[mi][ni][r];
                size_t cidx = (size_t)sC * bz + (size_t)gm * ldc + gn;
                if constexpr (MODE == 0) {
                    v = mish_f(v + bias[gn]);
                    ((unsigned short*)Cp)[cidx] = f2bf(v);
                } else if constexpr (MODE == 1) {
                    v += bias[(size_t)bz * biasStride + gn];
                    ((unsigned short*)Cp)[cidx] = f2bf(v);
                } else {
                    v += bias[gn] + resid[cidx];
                    ((float*)Cp)[cidx] = v;
                }
            }
}

// ---------------- launch ----------------

extern "C" void kernel_launch(void* const* d_in, const int* in_sizes, int n_in,
                              void* d_out, int out_size, void* d_ws, size_t ws_size,
                              hipStream_t stream) {
    const float* input = (const float*)d_in[0];
    const float* d_w   = (const float*)d_in[1];
    const float* d_g   = (const float*)d_in[2];
    const float* d_b   = (const float*)d_in[3];
    const float* p_w   = (const float*)d_in[4];
    const float* p_g   = (const float*)d_in[5];
    const float* p_b   = (const float*)d_in[6];
    const float* w1_w  = (const float*)d_in[7];
    const float* w1_b  = (const float*)d_in[8];
    const float* w2_w  = (const float*)d_in[9];
    const float* w2_b  = (const float*)d_in[10];
    float* out = (float*)d_out;

    char* ws = (char*)d_ws;
    size_t off = 0;
    auto alloc = [&](size_t bytes) {
        char* p = ws + off;
        off += (bytes + 255) & ~(size_t)255;
        return p;
    };
    float* norm_d        = (float*)alloc((size_t)BCNT * KW * 4);
    float* dwn_s         = (float*)alloc((size_t)BCNT * H1 * KW * 4);
    float* np_part       = (float*)alloc((size_t)BCNT * 8 * H2 * 4);
    float* inv_np        = (float*)alloc((size_t)BCNT * H2 * 4);
    unsigned short* inbf = (unsigned short*)alloc((size_t)BCNT * TT * DIN * 2);
    unsigned short* w1bf = (unsigned short*)alloc((size_t)H1 * DIN * 2);
    unsigned short* w2bf = (unsigned short*)alloc((size_t)DIN * H2 * 2);
    unsigned short* h    = (unsigned short*)alloc((size_t)BCNT * TT * H1 * 2);
    unsigned short* y    = (unsigned short*)alloc((size_t)BCNT * TT * H1 * 2);
    unsigned short* pwT  = (unsigned short*)alloc((size_t)BCNT * H2 * H1 * 2);
    unsigned short* zt   = (unsigned short*)alloc((size_t)BCNT * TT * H2 * 2);

    // f32 -> bf16 conversions (memory-bound, ~8 us total)
    k_cvt<<<(BCNT * TT * DIN / 4 + 255) / 256, 256, 0, stream>>>(input, inbf, BCNT * TT * DIN / 4);
    k_cvt<<<(H1 * DIN / 4 + 255) / 256, 256, 0, stream>>>(w1_w, w1bf, H1 * DIN / 4);
    k_cvt<<<(DIN * H2 / 4 + 255) / 256, 256, 0, stream>>>(w2_w, w2bf, DIN * H2 / 4);

    // weight prep
    k_norm_d<<<BCNT * KW, 256, 0, stream>>>(d_w, norm_d);
    k_dwn<<<(BCNT * H1 * KW) / 256, 256, 0, stream>>>(d_w, d_g, norm_d, dwn_s);
    k_norm_p_part<<<dim3(BCNT, H2 / 256, 8), 256, 0, stream>>>(p_w, np_part);
    k_norm_p_fin<<<dim3(BCNT, H2 / 256), 256, 0, stream>>>(np_part, inv_np);
    k_tpw<<<dim3(H1 / 32, H2 / 32, BCNT), 256, 0, stream>>>(p_w, inv_np, p_g, pwT);

    // G1: h = bf16(mish(input @ w1_w^T + w1_b)), (B*T, H1)
    gemm_nt<0><<<dim3(BCNT * TT / 128, H1 / 128, 1), 256, 0, stream>>>(
        inbf, w1bf, h, DIN, DIN, DIN, H1, 0, 0, 0, w1_b, 0, nullptr);

    // depthwise conv -> y (B*T, H1) bf16
    k_conv<<<dim3(TT / 128, H1 / 256, BCNT), 256, 0, stream>>>(h, dwn_s, d_b, y);

    // G2 (batched): zt[b,t,o] = sum_c y[b,t,c]*pwT[b,o,c] + p_b[b,o]
    gemm_nt<1><<<dim3(TT / 128, H2 / 128, BCNT), 256, 0, stream>>>(
        y, pwT, zt, H1, H1, H1, H2, (long)TT * H1, (long)H2 * H1, (long)TT * H2, p_b, H2, nullptr);

    // G3: out[b,t,d] = sum_o zt[b,t,o]*w2_w[d,o] + w2_b[d] + input
    gemm_nt<2><<<dim3(BCNT * TT / 128, DIN / 128, 1), 256, 0, stream>>>(
        zt, w2bf, out, H2, H2, H2, DIN, 0, 0, 0, w2_b, 0, input);
}

// Round 3
// 327.319 us; speedup vs baseline: 1.5191x; 1.0993x over previous
//
#include <hip/hip_runtime.h>

#define BCNT 16
#define TT 1024
#define DIN 384
#define H1 1024
#define H2 1024
#define KW 9

typedef __attribute__((ext_vector_type(8))) short bhalf8;   // 8 bf16 in 4 VGPRs
typedef __attribute__((ext_vector_type(4))) float f32x4;

typedef const __attribute__((address_space(1))) void* gas_ptr;
typedef __attribute__((address_space(3))) void* lds_ptr;

__device__ __forceinline__ float bf2f(unsigned short u) {
    return __uint_as_float(((unsigned int)u) << 16);
}
__device__ __forceinline__ unsigned short f2bf(float f) {
    unsigned int u = __float_as_uint(f);
    unsigned int r = (u + 0x7FFFu + ((u >> 16) & 1u)) >> 16;  // RNE
    return (unsigned short)r;
}
// mish(x) = x*tanh(log1p(e^x)) = x*(u^2+2u)/(u^2+2u+2), u=e^x  (exact algebra)
__device__ __forceinline__ float mish_f(float x) {
    if (x > 20.f) return x;           // tanh(softplus) == 1 to fp32 precision
    float u = __expf(x);
    float n = u * u + 2.f * u;
    return x * n / (n + 2.f);
}

// ---------------- prep kernels ----------------

__global__ __launch_bounds__(256) void k_cvt(const float* __restrict__ src,
                                             unsigned short* __restrict__ dst, int n4) {
    int i = blockIdx.x * 256 + threadIdx.x;
    if (i < n4) {
        float4 v = ((const float4*)src)[i];
        ushort4 o;
        o.x = f2bf(v.x); o.y = f2bf(v.y); o.z = f2bf(v.z); o.w = f2bf(v.w);
        ((ushort4*)dst)[i] = o;
    }
}

// norm over channels for each (b, k) tap of d_w (B,H1,1,K)
__global__ void k_norm_d(const float* __restrict__ d_w, float* __restrict__ norm_d) {
    int idx = blockIdx.x;           // b*KW + k
    int b = idx / KW, k = idx % KW;
    float s = 0.f;
    for (int c = threadIdx.x; c < H1; c += 256) {
        float v = d_w[((size_t)b * H1 + c) * KW + k];
        s += v * v;
    }
    __shared__ float red[256];
    red[threadIdx.x] = s; __syncthreads();
    for (int st = 128; st > 0; st >>= 1) {
        if (threadIdx.x < st) red[threadIdx.x] += red[threadIdx.x + st];
        __syncthreads();
    }
    if (threadIdx.x == 0) norm_d[idx] = sqrtf(red[0]);
}

// dwn_s[b,c,k] = d_w[b,c,0,k] / max(norm_d[b,k],1e-12) * d_g[b,c] * T
__global__ void k_dwn(const float* __restrict__ d_w, const float* __restrict__ d_g,
                      const float* __restrict__ norm_d, float* __restrict__ dwn_s) {
    int i = blockIdx.x * 256 + threadIdx.x;  // < B*H1*KW (exact)
    int k = i % KW;
    int c = (i / KW) % H1;
    int b = i / (KW * H1);
    float n = fmaxf(norm_d[b * KW + k], 1e-12f);
    dwn_s[i] = d_w[i] / n * d_g[b * H1 + c] * (float)TT;
}

// partial sums of p_w[b,:,o]^2 over c-chunks of 128 (8 chunks)
__global__ __launch_bounds__(256) void k_norm_p_part(const float* __restrict__ p_w,
                                                     float* __restrict__ part) {
    int o = blockIdx.y * 256 + threadIdx.x;
    int b = blockIdx.x, ch = blockIdx.z;
    float s = 0.f;
    for (int c = ch * 128; c < ch * 128 + 128; c++) {
        float v = p_w[((size_t)b * H1 + c) * H2 + o];
        s += v * v;
    }
    part[((size_t)(b * 8 + ch)) * H2 + o] = s;
}

__global__ __launch_bounds__(256) void k_norm_p_fin(const float* __restrict__ part,
                                                    float* __restrict__ inv_np) {
    int o = blockIdx.y * 256 + threadIdx.x;
    int b = blockIdx.x;
    float s = 0.f;
#pragma unroll
    for (int ch = 0; ch < 8; ch++) s += part[((size_t)(b * 8 + ch)) * H2 + o];
    inv_np[b * H2 + o] = 1.0f / fmaxf(sqrtf(s), 1e-12f);
}

// pwT[b,o,c] = bf16( p_w[b,c,o] * inv_np[b,o] * p_g[b,c] )
__global__ __launch_bounds__(256) void k_tpw(const float* __restrict__ p_w,
                                             const float* __restrict__ inv_np,
                                             const float* __restrict__ p_g,
                                             unsigned short* __restrict__ pwT) {
    __shared__ float tile[32][33];
    int tx = threadIdx.x & 31, ty = threadIdx.x >> 5;  // 32 x 8
    int c0 = blockIdx.x * 32, o0 = blockIdx.y * 32, b = blockIdx.z;
#pragma unroll
    for (int j = 0; j < 4; j++)
        tile[ty + j * 8][tx] = p_w[((size_t)b * H1 + c0 + ty + j * 8) * H2 + o0 + tx];
    __syncthreads();
#pragma unroll
    for (int j = 0; j < 4; j++) {
        int o = o0 + ty + j * 8, c = c0 + tx;
        float v = tile[tx][ty + j * 8] * inv_np[b * H2 + o] * p_g[(size_t)b * H1 + c];
        pwT[((size_t)b * H2 + o) * H1 + c] = f2bf(v);
    }
}

// depthwise conv along T, sliding window; 2 channels per thread (ushort2)
__global__ __launch_bounds__(256) void k_conv(const unsigned short* __restrict__ h,
                                              const float* __restrict__ dwn_s,
                                              const float* __restrict__ d_b,
                                              unsigned short* __restrict__ y) {
    int tid = threadIdx.x;
    int c2 = blockIdx.y * 256 + tid;       // pair index, H1/2 pairs
    int c = c2 * 2;
    int t0 = blockIdx.x * 64;
    int b = blockIdx.z;
    const ushort2* hb = (const ushort2*)(h + (size_t)b * TT * H1);
    ushort2* yb = (ushort2*)(y + (size_t)b * TT * H1);
    float k0[KW], k1[KW];
#pragma unroll
    for (int i = 0; i < KW; i++) {
        k0[i] = dwn_s[((size_t)b * H1 + c) * KW + i];
        k1[i] = dwn_s[((size_t)b * H1 + c + 1) * KW + i];
    }
    float db0 = d_b[b * H1 + c], db1 = d_b[b * H1 + c + 1];
    float w0[KW], w1[KW];
#pragma unroll
    for (int i = 0; i < 8; i++) {
        int t = t0 - 4 + i;
        if (t >= 0 && t < TT) {
            ushort2 v = hb[(size_t)t * (H1 / 2) + c2];
            w0[i] = bf2f(v.x); w1[i] = bf2f(v.y);
        } else { w0[i] = 0.f; w1[i] = 0.f; }
    }
    for (int j = 0; j < 64; j++) {
        int t = t0 + j;
        int tl = t + 4;
        if (tl < TT) {
            ushort2 v = hb[(size_t)tl * (H1 / 2) + c2];
            w0[8] = bf2f(v.x); w1[8] = bf2f(v.y);
        } else { w0[8] = 0.f; w1[8] = 0.f; }
        float a0 = db0, a1 = db1;
#pragma unroll
        for (int i = 0; i < KW; i++) { a0 += k0[i] * w0[i]; a1 += k1[i] * w1[i]; }
        ushort2 o; o.x = f2bf(a0); o.y = f2bf(a1);
        yb[(size_t)t * (H1 / 2) + c2] = o;
#pragma unroll
        for (int i = 0; i < 8; i++) { w0[i] = w0[i + 1]; w1[i] = w1[i + 1]; }
    }
}

// ---------------- bf16 NT MFMA GEMM, m97 structure ----------------
// C[m,n] = sum_k A[m,k]*B[n,k], both bf16 K-contiguous. 128x128 tile, BK=32.
// MODE 0: C=bf16(mish(v + bias[n]))
// MODE 1: C=bf16(v + bias[bz*biasStride+n])
// MODE 2: C=f32 (v + bias[n] + bf2f(residbf[idx]))
// SWIZ 1: 1-D grid 1024, XCD-aware decode — XCD k owns batches {2k,2k+1};
//         within a batch, x (t-tile) fastest so same-XCD consecutive blocks
//         share the B strip; whole batch working set (4 MB) fits one L2.
template <int MODE, int SWIZ>
__global__ __launch_bounds__(256) void gemm_nt(
    const unsigned short* __restrict__ A, const unsigned short* __restrict__ Bm,
    void* __restrict__ Cp, int Kdim, int lda, int ldb, int ldc,
    long sA, long sB, long sC,
    const float* __restrict__ bias, int biasStride,
    const unsigned short* __restrict__ residbf) {
    __shared__ __attribute__((aligned(16))) unsigned short Al[128 * 32];
    __shared__ __attribute__((aligned(16))) unsigned short Bl[128 * 32];

    const int tid = threadIdx.x;
    const int lane = tid & 63, wv = tid >> 6;

    int bx, by, bz;
    if constexpr (SWIZ) {
        int l = blockIdx.x;
        int xcd = l & 7, s = l >> 3;     // XCD = linear%8 (m09 round-robin heuristic)
        bz = xcd * 2 + (s >> 6);
        int u = s & 63;
        bx = u & 7; by = u >> 3;
    } else {
        bx = blockIdx.x; by = blockIdx.y; bz = blockIdx.z;
    }
    const int bm = bx * 128, bn = by * 128;

    const unsigned short* Ab = A + (size_t)sA * bz;
    const unsigned short* Bb = Bm + (size_t)sB * bz;

    // staging lane map: chunk = 16 rows; lane covers (row = lane/4, col = (lane&3)*8 elems)
    const int rS = lane >> 2;
    const int cS = (lane & 3) * 8;

    const int wm = (wv >> 1) * 64, wn = (wv & 1) * 64;
    const int l16 = lane & 15, quad = lane >> 4;

    f32x4 acc[4][4];
#pragma unroll
    for (int i = 0; i < 4; i++)
#pragma unroll
        for (int j = 0; j < 4; j++)
#pragma unroll
            for (int r = 0; r < 4; r++) acc[i][j][r] = 0.f;

    const int ktiles = Kdim / 32;
    for (int kt = 0; kt < ktiles; ++kt) {
        const int kofs = kt * 32 + cS;
#pragma unroll
        for (int i = 0; i < 2; i++) {
            const int ch = wv + i * 4;              // 8 chunks of 16 rows
            const unsigned short* ga = Ab + (size_t)(bm + ch * 16 + rS) * lda + kofs;
            __builtin_amdgcn_global_load_lds((gas_ptr)ga, (lds_ptr)&Al[ch * 512], 16, 0, 0);
            const unsigned short* gb = Bb + (size_t)(bn + ch * 16 + rS) * ldb + kofs;
            __builtin_amdgcn_global_load_lds((gas_ptr)gb, (lds_ptr)&Bl[ch * 512], 16, 0, 0);
        }
        __syncthreads();

        bhalf8 af[4], bf[4];
#pragma unroll
        for (int mi = 0; mi < 4; mi++)
            af[mi] = *(const bhalf8*)&Al[(wm + mi * 16 + l16) * 32 + quad * 8];
#pragma unroll
        for (int ni = 0; ni < 4; ni++)
            bf[ni] = *(const bhalf8*)&Bl[(wn + ni * 16 + l16) * 32 + quad * 8];
#pragma unroll
        for (int mi = 0; mi < 4; mi++)
#pragma unroll
            for (int ni = 0; ni < 4; ni++)
                acc[mi][ni] = __builtin_amdgcn_mfma_f32_16x16x32_bf16(af[mi], bf[ni],
                                                                     acc[mi][ni], 0, 0, 0);
        __syncthreads();
    }

    // epilogue: D row = quad*4+r, col = lane&15
#pragma unroll
    for (int mi = 0; mi < 4; mi++)
#pragma unroll
        for (int ni = 0; ni < 4; ni++)
#pragma unroll
            for (int r = 0; r < 4; r++) {
                int gm = bm + wm + mi * 16 + quad * 4 + r;
                int gn = bn + wn + ni * 16 + l16;
                float v = acc[mi][ni][r];
                size_t cidx = (size_t)sC * bz + (size_t)gm * ldc + gn;
                if constexpr (MODE == 0) {
                    v = mish_f(v + bias[gn]);
                    ((unsigned short*)Cp)[cidx] = f2bf(v);
                } else if constexpr (MODE == 1) {
                    v += bias[(size_t)bz * biasStride + gn];
                    ((unsigned short*)Cp)[cidx] = f2bf(v);
                } else {
                    v += bias[gn] + bf2f(residbf[cidx]);
                    ((float*)Cp)[cidx] = v;
                }
            }
}

// ---------------- launch ----------------

extern "C" void kernel_launch(void* const* d_in, const int* in_sizes, int n_in,
                              void* d_out, int out_size, void* d_ws, size_t ws_size,
                              hipStream_t stream) {
    const float* input = (const float*)d_in[0];
    const float* d_w   = (const float*)d_in[1];
    const float* d_g   = (const float*)d_in[2];
    const float* d_b   = (const float*)d_in[3];
    const float* p_w   = (const float*)d_in[4];
    const float* p_g   = (const float*)d_in[5];
    const float* p_b   = (const float*)d_in[6];
    const float* w1_w  = (const float*)d_in[7];
    const float* w1_b  = (const float*)d_in[8];
    const float* w2_w  = (const float*)d_in[9];
    const float* w2_b  = (const float*)d_in[10];
    float* out = (float*)d_out;

    char* ws = (char*)d_ws;
    size_t off = 0;
    auto alloc = [&](size_t bytes) {
        char* p = ws + off;
        off += (bytes + 255) & ~(size_t)255;
        return p;
    };
    float* norm_d        = (float*)alloc((size_t)BCNT * KW * 4);
    float* dwn_s         = (float*)alloc((size_t)BCNT * H1 * KW * 4);
    float* np_part       = (float*)alloc((size_t)BCNT * 8 * H2 * 4);
    float* inv_np        = (float*)alloc((size_t)BCNT * H2 * 4);
    unsigned short* inbf = (unsigned short*)alloc((size_t)BCNT * TT * DIN * 2);
    unsigned short* w1bf = (unsigned short*)alloc((size_t)H1 * DIN * 2);
    unsigned short* w2bf = (unsigned short*)alloc((size_t)DIN * H2 * 2);
    unsigned short* h    = (unsigned short*)alloc((size_t)BCNT * TT * H1 * 2);
    unsigned short* y    = (unsigned short*)alloc((size_t)BCNT * TT * H1 * 2);
    unsigned short* pwT  = (unsigned short*)alloc((size_t)BCNT * H2 * H1 * 2);
    unsigned short* zt   = (unsigned short*)alloc((size_t)BCNT * TT * H2 * 2);

    // f32 -> bf16 conversions
    k_cvt<<<(BCNT * TT * DIN / 4 + 255) / 256, 256, 0, stream>>>(input, inbf, BCNT * TT * DIN / 4);
    k_cvt<<<(H1 * DIN / 4 + 255) / 256, 256, 0, stream>>>(w1_w, w1bf, H1 * DIN / 4);
    k_cvt<<<(DIN * H2 / 4 + 255) / 256, 256, 0, stream>>>(w2_w, w2bf, DIN * H2 / 4);

    // weight prep
    k_norm_d<<<BCNT * KW, 256, 0, stream>>>(d_w, norm_d);
    k_dwn<<<(BCNT * H1 * KW) / 256, 256, 0, stream>>>(d_w, d_g, norm_d, dwn_s);
    k_norm_p_part<<<dim3(BCNT, H2 / 256, 8), 256, 0, stream>>>(p_w, np_part);
    k_norm_p_fin<<<dim3(BCNT, H2 / 256), 256, 0, stream>>>(np_part, inv_np);
    k_tpw<<<dim3(H1 / 32, H2 / 32, BCNT), 256, 0, stream>>>(p_w, inv_np, p_g, pwT);

    // G1: h = bf16(mish(input @ w1_w^T + w1_b)), (B*T, H1)
    gemm_nt<0, 0><<<dim3(BCNT * TT / 128, H1 / 128, 1), 256, 0, stream>>>(
        inbf, w1bf, h, DIN, DIN, DIN, H1, 0, 0, 0, w1_b, 0, nullptr);

    // depthwise conv -> y (B*T, H1) bf16
    k_conv<<<dim3(TT / 64, H1 / 512, BCNT), 256, 0, stream>>>(h, dwn_s, d_b, y);

    // G2 (batched, XCD-swizzled): zt[b,t,o] = sum_c y[b,t,c]*pwT[b,o,c] + p_b[b,o]
    gemm_nt<1, 1><<<dim3(1024, 1, 1), 256, 0, stream>>>(
        y, pwT, zt, H1, H1, H1, H2, (long)TT * H1, (long)H2 * H1, (long)TT * H2, p_b, H2, nullptr);

    // G3: out[b,t,d] = sum_o zt[b,t,o]*w2_w[d,o] + w2_b[d] + bf16(input)
    gemm_nt<2, 0><<<dim3(BCNT * TT / 128, DIN / 128, 1), 256, 0, stream>>>(
        zt, w2bf, out, H2, H2, H2, DIN, 0, 0, 0, w2_b, 0, inbf);
}

// Round 4
// 321.664 us; speedup vs baseline: 1.5458x; 1.0176x over previous
//
#include <hip/hip_runtime.h>

#define BCNT 16
#define TT 1024
#define DIN 384
#define H1 1024
#define H2 1024
#define KW 9

typedef __attribute__((ext_vector_type(8))) short bhalf8;   // 8 bf16 in 4 VGPRs
typedef __attribute__((ext_vector_type(4))) float f32x4;

typedef const __attribute__((address_space(1))) void* gas_ptr;
typedef __attribute__((address_space(3))) void* lds_ptr;

__device__ __forceinline__ float bf2f(unsigned short u) {
    return __uint_as_float(((unsigned int)u) << 16);
}
__device__ __forceinline__ unsigned short f2bf(float f) {
    unsigned int u = __float_as_uint(f);
    unsigned int r = (u + 0x7FFFu + ((u >> 16) & 1u)) >> 16;  // RNE
    return (unsigned short)r;
}
// mish(x) = x*tanh(log1p(e^x)) = x*(u^2+2u)/(u^2+2u+2), u=e^x  (exact algebra)
__device__ __forceinline__ float mish_f(float x) {
    if (x > 20.f) return x;
    float u = __expf(x);
    float n = u * u + 2.f * u;
    return x * n / (n + 2.f);
}

// ---------------- prep kernels ----------------

// fused f32->bf16 cvt for input, w1_w, w2_w (one launch)
__global__ __launch_bounds__(256) void k_cvt3(
    const float* __restrict__ s0, unsigned short* __restrict__ d0, int n0,
    const float* __restrict__ s1, unsigned short* __restrict__ d1, int n1,
    const float* __restrict__ s2, unsigned short* __restrict__ d2, int n2) {
    int i = blockIdx.x * 256 + threadIdx.x;
    const float* s; unsigned short* d; int j = i;
    if (i < n0) { s = s0; d = d0; }
    else if ((j = i - n0) < n1) { s = s1; d = d1; }
    else if ((j = i - n0 - n1) < n2) { s = s2; d = d2; }
    else return;
    float4 v = ((const float4*)s)[j];
    ushort4 o;
    o.x = f2bf(v.x); o.y = f2bf(v.y); o.z = f2bf(v.z); o.w = f2bf(v.w);
    ((ushort4*)d)[j] = o;
}

__global__ __launch_bounds__(256) void k_zero(float* __restrict__ p, int n) {
    int i = blockIdx.x * 256 + threadIdx.x;
    if (i < n) p[i] = 0.f;
}

// norm over channels for each (b, k) tap of d_w (B,H1,1,K)
__global__ void k_norm_d(const float* __restrict__ d_w, float* __restrict__ norm_d) {
    int idx = blockIdx.x;           // b*KW + k
    int b = idx / KW, k = idx % KW;
    float s = 0.f;
    for (int c = threadIdx.x; c < H1; c += 256) {
        float v = d_w[((size_t)b * H1 + c) * KW + k];
        s += v * v;
    }
    __shared__ float red[256];
    red[threadIdx.x] = s; __syncthreads();
    for (int st = 128; st > 0; st >>= 1) {
        if (threadIdx.x < st) red[threadIdx.x] += red[threadIdx.x + st];
        __syncthreads();
    }
    if (threadIdx.x == 0) norm_d[idx] = sqrtf(red[0]);
}

// dwn_s[b,c,k] = d_w[b,c,0,k] / max(norm_d[b,k],1e-12) * d_g[b,c] * T
__global__ void k_dwn(const float* __restrict__ d_w, const float* __restrict__ d_g,
                      const float* __restrict__ norm_d, float* __restrict__ dwn_s) {
    int i = blockIdx.x * 256 + threadIdx.x;
    int k = i % KW;
    int c = (i / KW) % H1;
    int b = i / (KW * H1);
    float n = fmaxf(norm_d[b * KW + k], 1e-12f);
    dwn_s[i] = d_w[i] / n * d_g[b * H1 + c] * (float)TT;
}

// transpose+scale p_w AND accumulate per-(b,o) sum of squares (for inv_np).
// pwTu[b,o,c] = bf16(p_w[b,c,o] * p_g[b,c]);  sumsq[b,o] += sum_c p_w^2
__global__ __launch_bounds__(256) void k_tpw2(const float* __restrict__ p_w,
                                              const float* __restrict__ p_g,
                                              unsigned short* __restrict__ pwTu,
                                              float* __restrict__ sumsq) {
    __shared__ float tile[32][33];
    __shared__ float red[8][32];
    int tx = threadIdx.x & 31, ty = threadIdx.x >> 5;  // 32 x 8
    int c0 = blockIdx.x * 32, o0 = blockIdx.y * 32, b = blockIdx.z;
    float s = 0.f;
#pragma unroll
    for (int j = 0; j < 4; j++) {
        float v = p_w[((size_t)b * H1 + c0 + ty + j * 8) * H2 + o0 + tx];
        tile[ty + j * 8][tx] = v;
        s += v * v;                 // partial ||p_w[b,:,o0+tx]||^2 over this c-slice
    }
    red[ty][tx] = s;
    __syncthreads();
    if (ty == 0) {
        float t = 0.f;
#pragma unroll
        for (int r = 0; r < 8; r++) t += red[r][tx];
        atomicAdd(&sumsq[(size_t)b * H2 + o0 + tx], t);
    }
#pragma unroll
    for (int j = 0; j < 4; j++) {
        int o = o0 + ty + j * 8, c = c0 + tx;
        float v = tile[tx][ty + j * 8] * p_g[(size_t)b * H1 + c];
        pwTu[((size_t)b * H2 + o) * H1 + c] = f2bf(v);
    }
}

__global__ __launch_bounds__(256) void k_inv(const float* __restrict__ sumsq,
                                             float* __restrict__ inv_np, int n) {
    int i = blockIdx.x * 256 + threadIdx.x;
    if (i < n) inv_np[i] = 1.0f / fmaxf(sqrtf(sumsq[i]), 1e-12f);
}

// depthwise conv along T, sliding window; 2 channels per thread (ushort2)
__global__ __launch_bounds__(256) void k_conv(const unsigned short* __restrict__ h,
                                              const float* __restrict__ dwn_s,
                                              const float* __restrict__ d_b,
                                              unsigned short* __restrict__ y) {
    int tid = threadIdx.x;
    int c2 = blockIdx.y * 256 + tid;
    int c = c2 * 2;
    int t0 = blockIdx.x * 64;
    int b = blockIdx.z;
    const ushort2* hb = (const ushort2*)(h + (size_t)b * TT * H1);
    ushort2* yb = (ushort2*)(y + (size_t)b * TT * H1);
    float k0[KW], k1[KW];
#pragma unroll
    for (int i = 0; i < KW; i++) {
        k0[i] = dwn_s[((size_t)b * H1 + c) * KW + i];
        k1[i] = dwn_s[((size_t)b * H1 + c + 1) * KW + i];
    }
    float db0 = d_b[b * H1 + c], db1 = d_b[b * H1 + c + 1];
    float w0[KW], w1[KW];
#pragma unroll
    for (int i = 0; i < 8; i++) {
        int t = t0 - 4 + i;
        if (t >= 0 && t < TT) {
            ushort2 v = hb[(size_t)t * (H1 / 2) + c2];
            w0[i] = bf2f(v.x); w1[i] = bf2f(v.y);
        } else { w0[i] = 0.f; w1[i] = 0.f; }
    }
    for (int j = 0; j < 64; j++) {
        int t = t0 + j;
        int tl = t + 4;
        if (tl < TT) {
            ushort2 v = hb[(size_t)tl * (H1 / 2) + c2];
            w0[8] = bf2f(v.x); w1[8] = bf2f(v.y);
        } else { w0[8] = 0.f; w1[8] = 0.f; }
        float a0 = db0, a1 = db1;
#pragma unroll
        for (int i = 0; i < KW; i++) { a0 += k0[i] * w0[i]; a1 += k1[i] * w1[i]; }
        ushort2 o; o.x = f2bf(a0); o.y = f2bf(a1);
        yb[(size_t)t * (H1 / 2) + c2] = o;
#pragma unroll
        for (int i = 0; i < 8; i++) { w0[i] = w0[i + 1]; w1[i] = w1[i + 1]; }
    }
}

// ---------------- bf16 NT MFMA GEMM: 128x64 tile, 128 threads (2 waves) ----------------
// C[m,n] = sum_k A[m,k]*B[n,k], bf16 K-contiguous. BK=32. Each wave: 64 rows x 64 cols.
// LDS 12 KB -> 6 blocks/CU (reg-limited ~3 waves/SIMD) -> 1536 resident slots.
// XOR bank swizzle: column-group stored at (grp ^ ((row&15)>>1)&3) -> 2-way max conflict.
// MODE 0: C=bf16(mish(v + bias[n]))
// MODE 1: C=bf16(v*scale[bz*str+n] + bias[bz*str+n])
// MODE 2: C=f32 (v + bias[n] + bf2f(residbf[idx]))
template <int MODE, int SWIZ>
__global__ __launch_bounds__(128) void gemm_nt(
    const unsigned short* __restrict__ A, const unsigned short* __restrict__ Bm,
    void* __restrict__ Cp, int Kdim, int lda, int ldb, int ldc,
    long sA, long sB, long sC,
    const float* __restrict__ bias, int biasStride,
    const float* __restrict__ scale,
    const unsigned short* __restrict__ residbf) {
    __shared__ __attribute__((aligned(16))) unsigned short Al[128 * 32];
    __shared__ __attribute__((aligned(16))) unsigned short Bl[64 * 32];

    const int tid = threadIdx.x;
    const int lane = tid & 63, wv = tid >> 6;  // 2 waves

    int bx, by, bz;
    if constexpr (SWIZ) {
        // G2: 2048 blocks. XCD k owns batches {2k,2k+1}; m-tile fastest.
        int l = blockIdx.x;
        int xcd = l & 7, s = l >> 3;       // s: 0..255
        bz = xcd * 2 + (s >> 7);
        int u = s & 127;
        bx = u & 7; by = u >> 3;           // bx: m-tile 0..7, by: n-tile 0..15
    } else {
        bx = blockIdx.x; by = blockIdx.y; bz = blockIdx.z;
    }
    const int bm = bx * 128, bn = by * 64;

    const unsigned short* Ab = A + (size_t)sA * bz;
    const unsigned short* Bb = Bm + (size_t)sB * bz;

    // staging map: chunk = 16 rows; lane -> (row=lane>>2, slot=lane&3), slot holds
    // global col-group (slot ^ ((row>>1)&3)) (XOR bank swizzle)
    const int rS = lane >> 2;
    const int cS = (((lane & 3) ^ ((rS >> 1) & 3)) & 3) * 8;

    const int wm = wv * 64;                 // wave's row origin
    const int l16 = lane & 15, quad = lane >> 4;
    const int fr = (l16 >> 1) & 3;          // read-side XOR

    f32x4 acc[4][4];
#pragma unroll
    for (int i = 0; i < 4; i++)
#pragma unroll
        for (int j = 0; j < 4; j++)
#pragma unroll
            for (int r = 0; r < 4; r++) acc[i][j][r] = 0.f;

    const int ktiles = Kdim / 32;
    for (int kt = 0; kt < ktiles; ++kt) {
        const int kofs = kt * 32 + cS;
        // A: 8 chunks of 16 rows, 4 per wave
#pragma unroll
        for (int i = 0; i < 4; i++) {
            const int ch = i * 2 + wv;
            const unsigned short* ga = Ab + (size_t)(bm + ch * 16 + rS) * lda + kofs;
            __builtin_amdgcn_global_load_lds((gas_ptr)ga, (lds_ptr)&Al[ch * 512], 16, 0, 0);
        }
        // B: 4 chunks, 2 per wave
#pragma unroll
        for (int i = 0; i < 2; i++) {
            const int ch = i * 2 + wv;
            const unsigned short* gb = Bb + (size_t)(bn + ch * 16 + rS) * ldb + kofs;
            __builtin_amdgcn_global_load_lds((gas_ptr)gb, (lds_ptr)&Bl[ch * 512], 16, 0, 0);
        }
        __syncthreads();

        bhalf8 af[4], bf[4];
#pragma unroll
        for (int mi = 0; mi < 4; mi++)
            af[mi] = *(const bhalf8*)&Al[(wm + mi * 16 + l16) * 32 + ((quad ^ fr) & 3) * 8];
#pragma unroll
        for (int ni = 0; ni < 4; ni++)
            bf[ni] = *(const bhalf8*)&Bl[(ni * 16 + l16) * 32 + ((quad ^ fr) & 3) * 8];
#pragma unroll
        for (int mi = 0; mi < 4; mi++)
#pragma unroll
            for (int ni = 0; ni < 4; ni++)
                acc[mi][ni] = __builtin_amdgcn_mfma_f32_16x16x32_bf16(af[mi], bf[ni],
                                                                     acc[mi][ni], 0, 0, 0);
        __syncthreads();
    }

    // epilogue: D row = quad*4+r, col = lane&15
#pragma unroll
    for (int mi = 0; mi < 4; mi++)
#pragma unroll
        for (int ni = 0; ni < 4; ni++)
#pragma unroll
            for (int r = 0; r < 4; r++) {
                int gm = bm + wm + mi * 16 + quad * 4 + r;
                int gn = bn + ni * 16 + l16;
                float v = acc[mi][ni][r];
                size_t cidx = (size_t)sC * bz + (size_t)gm * ldc + gn;
                if constexpr (MODE == 0) {
                    v = mish_f(v + bias[gn]);
                    ((unsigned short*)Cp)[cidx] = f2bf(v);
                } else if constexpr (MODE == 1) {
                    size_t si = (size_t)bz * biasStride + gn;
                    v = v * scale[si] + bias[si];
                    ((unsigned short*)Cp)[cidx] = f2bf(v);
                } else {
                    v += bias[gn] + bf2f(residbf[cidx]);
                    ((float*)Cp)[cidx] = v;
                }
            }
}

// ---------------- launch ----------------

extern "C" void kernel_launch(void* const* d_in, const int* in_sizes, int n_in,
                              void* d_out, int out_size, void* d_ws, size_t ws_size,
                              hipStream_t stream) {
    const float* input = (const float*)d_in[0];
    const float* d_w   = (const float*)d_in[1];
    const float* d_g   = (const float*)d_in[2];
    const float* d_b   = (const float*)d_in[3];
    const float* p_w   = (const float*)d_in[4];
    const float* p_g   = (const float*)d_in[5];
    const float* p_b   = (const float*)d_in[6];
    const float* w1_w  = (const float*)d_in[7];
    const float* w1_b  = (const float*)d_in[8];
    const float* w2_w  = (const float*)d_in[9];
    const float* w2_b  = (const float*)d_in[10];
    float* out = (float*)d_out;

    char* ws = (char*)d_ws;
    size_t off = 0;
    auto alloc = [&](size_t bytes) {
        char* p = ws + off;
        off += (bytes + 255) & ~(size_t)255;
        return p;
    };
    float* norm_d        = (float*)alloc((size_t)BCNT * KW * 4);
    float* dwn_s         = (float*)alloc((size_t)BCNT * H1 * KW * 4);
    float* sumsq         = (float*)alloc((size_t)BCNT * H2 * 4);
    float* inv_np        = (float*)alloc((size_t)BCNT * H2 * 4);
    unsigned short* inbf = (unsigned short*)alloc((size_t)BCNT * TT * DIN * 2);
    unsigned short* w1bf = (unsigned short*)alloc((size_t)H1 * DIN * 2);
    unsigned short* w2bf = (unsigned short*)alloc((size_t)DIN * H2 * 2);
    unsigned short* h    = (unsigned short*)alloc((size_t)BCNT * TT * H1 * 2);
    unsigned short* y    = (unsigned short*)alloc((size_t)BCNT * TT * H1 * 2);
    unsigned short* pwTu = (unsigned short*)alloc((size_t)BCNT * H2 * H1 * 2);
    unsigned short* zt   = (unsigned short*)alloc((size_t)BCNT * TT * H2 * 2);

    // f32 -> bf16 conversions (one fused launch)
    const int n4_in = BCNT * TT * DIN / 4, n4_w1 = H1 * DIN / 4, n4_w2 = DIN * H2 / 4;
    k_cvt3<<<(n4_in + n4_w1 + n4_w2 + 255) / 256, 256, 0, stream>>>(
        input, inbf, n4_in, w1_w, w1bf, n4_w1, w2_w, w2bf, n4_w2);

    // weight prep
    k_zero<<<(BCNT * H2 + 255) / 256, 256, 0, stream>>>(sumsq, BCNT * H2);
    k_norm_d<<<BCNT * KW, 256, 0, stream>>>(d_w, norm_d);
    k_dwn<<<(BCNT * H1 * KW) / 256, 256, 0, stream>>>(d_w, d_g, norm_d, dwn_s);
    k_tpw2<<<dim3(H1 / 32, H2 / 32, BCNT), 256, 0, stream>>>(p_w, p_g, pwTu, sumsq);
    k_inv<<<(BCNT * H2 + 255) / 256, 256, 0, stream>>>(sumsq, inv_np, BCNT * H2);

    // G1: h = bf16(mish(input @ w1_w^T + w1_b)), (B*T, H1); 2048 blocks
    gemm_nt<0, 0><<<dim3(BCNT * TT / 128, H1 / 64, 1), 128, 0, stream>>>(
        inbf, w1bf, h, DIN, DIN, DIN, H1, 0, 0, 0, w1_b, 0, nullptr, nullptr);

    // depthwise conv -> y (B*T, H1) bf16
    k_conv<<<dim3(TT / 64, H1 / 512, BCNT), 256, 0, stream>>>(h, dwn_s, d_b, y);

    // G2 (batched, XCD-swizzled, 2048 blocks): zt[b,t,o] = inv_np[b,o]*(y . pwTu) + p_b[b,o]
    gemm_nt<1, 1><<<dim3(2048, 1, 1), 128, 0, stream>>>(
        y, pwTu, zt, H1, H1, H1, H2, (long)TT * H1, (long)H2 * H1, (long)TT * H2,
        p_b, H2, inv_np, nullptr);

    // G3: out[b,t,d] = sum_o zt[b,t,o]*w2_w[d,o] + w2_b[d] + bf16(input); 768 blocks
    gemm_nt<2, 0><<<dim3(BCNT * TT / 128, DIN / 64, 1), 128, 0, stream>>>(
        zt, w2bf, out, H2, H2, H2, DIN, 0, 0, 0, w2_b, 0, nullptr, inbf);
}

// Round 5
// 289.336 us; speedup vs baseline: 1.7185x; 1.1117x over previous
//
#include <hip/hip_runtime.h>

#define BCNT 16
#define TT 1024
#define DIN 384
#define H1 1024
#define H2 1024
#define KW 9

typedef __attribute__((ext_vector_type(8))) short bhalf8;   // 8 bf16 in 4 VGPRs
typedef __attribute__((ext_vector_type(4))) float f32x4;

typedef const __attribute__((address_space(1))) void* gas_ptr;
typedef __attribute__((address_space(3))) void* lds_ptr;

__device__ __forceinline__ float bf2f(unsigned short u) {
    return __uint_as_float(((unsigned int)u) << 16);
}
__device__ __forceinline__ unsigned short f2bf(float f) {
    unsigned int u = __float_as_uint(f);
    unsigned int r = (u + 0x7FFFu + ((u >> 16) & 1u)) >> 16;  // RNE
    return (unsigned short)r;
}
// mish(x) = x*tanh(log1p(e^x)) = x*(u^2+2u)/(u^2+2u+2), u=e^x  (exact algebra)
__device__ __forceinline__ float mish_f(float x) {
    if (x > 20.f) return x;
    float u = __expf(x);
    float n = u * u + 2.f * u;
    return x * n / (n + 2.f);
}

// ---------------- prep kernels ----------------

// fused f32->bf16 cvt for input, w1_w, w2_w (one launch)
__global__ __launch_bounds__(256) void k_cvt3(
    const float* __restrict__ s0, unsigned short* __restrict__ d0, int n0,
    const float* __restrict__ s1, unsigned short* __restrict__ d1, int n1,
    const float* __restrict__ s2, unsigned short* __restrict__ d2, int n2) {
    int i = blockIdx.x * 256 + threadIdx.x;
    const float* s; unsigned short* d; int j = i;
    if (i < n0) { s = s0; d = d0; }
    else if ((j = i - n0) < n1) { s = s1; d = d1; }
    else if ((j = i - n0 - n1) < n2) { s = s2; d = d2; }
    else return;
    float4 v = ((const float4*)s)[j];
    ushort4 o;
    o.x = f2bf(v.x); o.y = f2bf(v.y); o.z = f2bf(v.z); o.w = f2bf(v.w);
    ((ushort4*)d)[j] = o;
}

__global__ __launch_bounds__(256) void k_zero(float* __restrict__ p, int n) {
    int i = blockIdx.x * 256 + threadIdx.x;
    if (i < n) p[i] = 0.f;
}

// norm over channels for each (b, k) tap of d_w (B,H1,1,K)
__global__ void k_norm_d(const float* __restrict__ d_w, float* __restrict__ norm_d) {
    int idx = blockIdx.x;           // b*KW + k
    int b = idx / KW, k = idx % KW;
    float s = 0.f;
    for (int c = threadIdx.x; c < H1; c += 256) {
        float v = d_w[((size_t)b * H1 + c) * KW + k];
        s += v * v;
    }
    __shared__ float red[256];
    red[threadIdx.x] = s; __syncthreads();
    for (int st = 128; st > 0; st >>= 1) {
        if (threadIdx.x < st) red[threadIdx.x] += red[threadIdx.x + st];
        __syncthreads();
    }
    if (threadIdx.x == 0) norm_d[idx] = sqrtf(red[0]);
}

// dwn_s[b,c,k] = d_w[b,c,0,k] / max(norm_d[b,k],1e-12) * d_g[b,c] * T
__global__ void k_dwn(const float* __restrict__ d_w, const float* __restrict__ d_g,
                      const float* __restrict__ norm_d, float* __restrict__ dwn_s) {
    int i = blockIdx.x * 256 + threadIdx.x;
    int k = i % KW;
    int c = (i / KW) % H1;
    int b = i / (KW * H1);
    float n = fmaxf(norm_d[b * KW + k], 1e-12f);
    dwn_s[i] = d_w[i] / n * d_g[b * H1 + c] * (float)TT;
}

// transpose+scale p_w AND accumulate per-(b,o) sum of squares (for inv_np).
__global__ __launch_bounds__(256) void k_tpw2(const float* __restrict__ p_w,
                                              const float* __restrict__ p_g,
                                              unsigned short* __restrict__ pwTu,
                                              float* __restrict__ sumsq) {
    __shared__ float tile[32][33];
    __shared__ float red[8][32];
    int tx = threadIdx.x & 31, ty = threadIdx.x >> 5;  // 32 x 8
    int c0 = blockIdx.x * 32, o0 = blockIdx.y * 32, b = blockIdx.z;
    float s = 0.f;
#pragma unroll
    for (int j = 0; j < 4; j++) {
        float v = p_w[((size_t)b * H1 + c0 + ty + j * 8) * H2 + o0 + tx];
        tile[ty + j * 8][tx] = v;
        s += v * v;
    }
    red[ty][tx] = s;
    __syncthreads();
    if (ty == 0) {
        float t = 0.f;
#pragma unroll
        for (int r = 0; r < 8; r++) t += red[r][tx];
        atomicAdd(&sumsq[(size_t)b * H2 + o0 + tx], t);
    }
#pragma unroll
    for (int j = 0; j < 4; j++) {
        int o = o0 + ty + j * 8, c = c0 + tx;
        float v = tile[tx][ty + j * 8] * p_g[(size_t)b * H1 + c];
        pwTu[((size_t)b * H2 + o) * H1 + c] = f2bf(v);
    }
}

__global__ __launch_bounds__(256) void k_inv(const float* __restrict__ sumsq,
                                             float* __restrict__ inv_np, int n) {
    int i = blockIdx.x * 256 + threadIdx.x;
    if (i < n) inv_np[i] = 1.0f / fmaxf(sqrtf(sumsq[i]), 1e-12f);
}

// depthwise conv along T, sliding window; 2 channels per thread (ushort2)
__global__ __launch_bounds__(256) void k_conv(const unsigned short* __restrict__ h,
                                              const float* __restrict__ dwn_s,
                                              const float* __restrict__ d_b,
                                              unsigned short* __restrict__ y) {
    int tid = threadIdx.x;
    int c2 = blockIdx.y * 256 + tid;
    int c = c2 * 2;
    int t0 = blockIdx.x * 64;
    int b = blockIdx.z;
    const ushort2* hb = (const ushort2*)(h + (size_t)b * TT * H1);
    ushort2* yb = (ushort2*)(y + (size_t)b * TT * H1);
    float k0[KW], k1[KW];
#pragma unroll
    for (int i = 0; i < KW; i++) {
        k0[i] = dwn_s[((size_t)b * H1 + c) * KW + i];
        k1[i] = dwn_s[((size_t)b * H1 + c + 1) * KW + i];
    }
    float db0 = d_b[b * H1 + c], db1 = d_b[b * H1 + c + 1];
    float w0[KW], w1[KW];
#pragma unroll
    for (int i = 0; i < 8; i++) {
        int t = t0 - 4 + i;
        if (t >= 0 && t < TT) {
            ushort2 v = hb[(size_t)t * (H1 / 2) + c2];
            w0[i] = bf2f(v.x); w1[i] = bf2f(v.y);
        } else { w0[i] = 0.f; w1[i] = 0.f; }
    }
    for (int j = 0; j < 64; j++) {
        int t = t0 + j;
        int tl = t + 4;
        if (tl < TT) {
            ushort2 v = hb[(size_t)tl * (H1 / 2) + c2];
            w0[8] = bf2f(v.x); w1[8] = bf2f(v.y);
        } else { w0[8] = 0.f; w1[8] = 0.f; }
        float a0 = db0, a1 = db1;
#pragma unroll
        for (int i = 0; i < KW; i++) { a0 += k0[i] * w0[i]; a1 += k1[i] * w1[i]; }
        ushort2 o; o.x = f2bf(a0); o.y = f2bf(a1);
        yb[(size_t)t * (H1 / 2) + c2] = o;
#pragma unroll
        for (int i = 0; i < 8; i++) { w0[i] = w0[i + 1]; w1[i] = w1[i + 1]; }
    }
}

// ---------------- bf16 NT MFMA GEMM: 128x128 tile, 256 threads, 4 blocks/CU ----------------
// C[m,n] = sum_k A[m,k]*B[n,k], bf16 K-contiguous. BK=32. Wave = 64x64 subtile.
// __launch_bounds__(256,4): cap unified regs at 128 (64 acc + ~50 live) -> 4 blocks/CU
// -> 1024 resident blocks -> G1/G2 grids run in ONE phase (tail eliminated).
// XOR bank swizzle on LDS col-group -> 0 conflicts (verified R4).
// MODE 0: C=bf16(mish(v + bias[n]))
// MODE 1: C=bf16(v*scale[bz*str+n] + bias[bz*str+n])
// MODE 2: C=f32 (v + bias[n] + bf2f(residbf[idx]))
template <int MODE, int SWIZ>
__global__ __launch_bounds__(256, 4) void gemm_nt(
    const unsigned short* __restrict__ A, const unsigned short* __restrict__ Bm,
    void* __restrict__ Cp, int Kdim, int lda, int ldb, int ldc,
    long sA, long sB, long sC,
    const float* __restrict__ bias, int biasStride,
    const float* __restrict__ scale,
    const unsigned short* __restrict__ residbf) {
    __shared__ __attribute__((aligned(16))) unsigned short Al[128 * 32];
    __shared__ __attribute__((aligned(16))) unsigned short Bl[128 * 32];

    const int tid = threadIdx.x;
    const int lane = tid & 63, wv = tid >> 6;  // 4 waves

    int bx, by, bz;
    if constexpr (SWIZ) {
        // G2: 1024 blocks. XCD k owns batches {2k,2k+1}; m-tile fastest.
        int l = blockIdx.x;
        int xcd = l & 7, s = l >> 3;       // s: 0..127
        bz = xcd * 2 + (s >> 6);
        int u = s & 63;
        bx = u & 7; by = u >> 3;
    } else {
        bx = blockIdx.x; by = blockIdx.y; bz = blockIdx.z;
    }
    const int bm = bx * 128, bn = by * 128;

    const unsigned short* Ab = A + (size_t)sA * bz;
    const unsigned short* Bb = Bm + (size_t)sB * bz;

    // staging map: chunk = 16 rows; lane -> (row = lane>>2, slot = lane&3);
    // slot stores global col-group (slot ^ ((row>>1)&3))  [XOR bank swizzle]
    const int rS = lane >> 2;
    const int cS = (((lane & 3) ^ ((rS >> 1) & 3)) & 3) * 8;

    const int wm = (wv >> 1) * 64, wn = (wv & 1) * 64;
    const int l16 = lane & 15, quad = lane >> 4;
    const int fr = (l16 >> 1) & 3;          // read-side XOR

    f32x4 acc[4][4];
#pragma unroll
    for (int i = 0; i < 4; i++)
#pragma unroll
        for (int j = 0; j < 4; j++)
#pragma unroll
            for (int r = 0; r < 4; r++) acc[i][j][r] = 0.f;

    const int ktiles = Kdim / 32;
    for (int kt = 0; kt < ktiles; ++kt) {
        const int kofs = kt * 32 + cS;
#pragma unroll
        for (int i = 0; i < 2; i++) {
            const int ch = wv + i * 4;              // 8 chunks of 16 rows
            const unsigned short* ga = Ab + (size_t)(bm + ch * 16 + rS) * lda + kofs;
            __builtin_amdgcn_global_load_lds((gas_ptr)ga, (lds_ptr)&Al[ch * 512], 16, 0, 0);
            const unsigned short* gb = Bb + (size_t)(bn + ch * 16 + rS) * ldb + kofs;
            __builtin_amdgcn_global_load_lds((gas_ptr)gb, (lds_ptr)&Bl[ch * 512], 16, 0, 0);
        }
        __syncthreads();

        bhalf8 af[4], bf[4];
#pragma unroll
        for (int mi = 0; mi < 4; mi++)
            af[mi] = *(const bhalf8*)&Al[(wm + mi * 16 + l16) * 32 + ((quad ^ fr) & 3) * 8];
#pragma unroll
        for (int ni = 0; ni < 4; ni++)
            bf[ni] = *(const bhalf8*)&Bl[(wn + ni * 16 + l16) * 32 + ((quad ^ fr) & 3) * 8];
#pragma unroll
        for (int mi = 0; mi < 4; mi++)
#pragma unroll
            for (int ni = 0; ni < 4; ni++)
                acc[mi][ni] = __builtin_amdgcn_mfma_f32_16x16x32_bf16(af[mi], bf[ni],
                                                                     acc[mi][ni], 0, 0, 0);
        __syncthreads();
    }

    // epilogue: D row = quad*4+r, col = lane&15
#pragma unroll
    for (int mi = 0; mi < 4; mi++)
#pragma unroll
        for (int ni = 0; ni < 4; ni++)
#pragma unroll
            for (int r = 0; r < 4; r++) {
                int gm = bm + wm + mi * 16 + quad * 4 + r;
                int gn = bn + wn + ni * 16 + l16;
                float v = acc[mi][ni][r];
                size_t cidx = (size_t)sC * bz + (size_t)gm * ldc + gn;
                if constexpr (MODE == 0) {
                    v = mish_f(v + bias[gn]);
                    ((unsigned short*)Cp)[cidx] = f2bf(v);
                } else if constexpr (MODE == 1) {
                    size_t si = (size_t)bz * biasStride + gn;
                    v = v * scale[si] + bias[si];
                    ((unsigned short*)Cp)[cidx] = f2bf(v);
                } else {
                    v += bias[gn] + bf2f(residbf[cidx]);
                    ((float*)Cp)[cidx] = v;
                }
            }
}

// ---------------- launch ----------------

extern "C" void kernel_launch(void* const* d_in, const int* in_sizes, int n_in,
                              void* d_out, int out_size, void* d_ws, size_t ws_size,
                              hipStream_t stream) {
    const float* input = (const float*)d_in[0];
    const float* d_w   = (const float*)d_in[1];
    const float* d_g   = (const float*)d_in[2];
    const float* d_b   = (const float*)d_in[3];
    const float* p_w   = (const float*)d_in[4];
    const float* p_g   = (const float*)d_in[5];
    const float* p_b   = (const float*)d_in[6];
    const float* w1_w  = (const float*)d_in[7];
    const float* w1_b  = (const float*)d_in[8];
    const float* w2_w  = (const float*)d_in[9];
    const float* w2_b  = (const float*)d_in[10];
    float* out = (float*)d_out;

    char* ws = (char*)d_ws;
    size_t off = 0;
    auto alloc = [&](size_t bytes) {
        char* p = ws + off;
        off += (bytes + 255) & ~(size_t)255;
        return p;
    };
    float* norm_d        = (float*)alloc((size_t)BCNT * KW * 4);
    float* dwn_s         = (float*)alloc((size_t)BCNT * H1 * KW * 4);
    float* sumsq         = (float*)alloc((size_t)BCNT * H2 * 4);
    float* inv_np        = (float*)alloc((size_t)BCNT * H2 * 4);
    unsigned short* inbf = (unsigned short*)alloc((size_t)BCNT * TT * DIN * 2);
    unsigned short* w1bf = (unsigned short*)alloc((size_t)H1 * DIN * 2);
    unsigned short* w2bf = (unsigned short*)alloc((size_t)DIN * H2 * 2);
    unsigned short* h    = (unsigned short*)alloc((size_t)BCNT * TT * H1 * 2);
    unsigned short* y    = (unsigned short*)alloc((size_t)BCNT * TT * H1 * 2);
    unsigned short* pwTu = (unsigned short*)alloc((size_t)BCNT * H2 * H1 * 2);
    unsigned short* zt   = (unsigned short*)alloc((size_t)BCNT * TT * H2 * 2);

    // f32 -> bf16 conversions (one fused launch)
    const int n4_in = BCNT * TT * DIN / 4, n4_w1 = H1 * DIN / 4, n4_w2 = DIN * H2 / 4;
    k_cvt3<<<(n4_in + n4_w1 + n4_w2 + 255) / 256, 256, 0, stream>>>(
        input, inbf, n4_in, w1_w, w1bf, n4_w1, w2_w, w2bf, n4_w2);

    // weight prep
    k_zero<<<(BCNT * H2 + 255) / 256, 256, 0, stream>>>(sumsq, BCNT * H2);
    k_norm_d<<<BCNT * KW, 256, 0, stream>>>(d_w, norm_d);
    k_dwn<<<(BCNT * H1 * KW) / 256, 256, 0, stream>>>(d_w, d_g, norm_d, dwn_s);
    k_tpw2<<<dim3(H1 / 32, H2 / 32, BCNT), 256, 0, stream>>>(p_w, p_g, pwTu, sumsq);
    k_inv<<<(BCNT * H2 + 255) / 256, 256, 0, stream>>>(sumsq, inv_np, BCNT * H2);

    // G1: h = bf16(mish(input @ w1_w^T + w1_b)), (B*T, H1); 1024 blocks, one phase
    gemm_nt<0, 0><<<dim3(BCNT * TT / 128, H1 / 128, 1), 256, 0, stream>>>(
        inbf, w1bf, h, DIN, DIN, DIN, H1, 0, 0, 0, w1_b, 0, nullptr, nullptr);

    // depthwise conv -> y (B*T, H1) bf16
    k_conv<<<dim3(TT / 64, H1 / 512, BCNT), 256, 0, stream>>>(h, dwn_s, d_b, y);

    // G2 (batched, XCD-swizzled, 1024 blocks, one phase):
    // zt[b,t,o] = inv_np[b,o]*(y . pwTu) + p_b[b,o]
    gemm_nt<1, 1><<<dim3(1024, 1, 1), 256, 0, stream>>>(
        y, pwTu, zt, H1, H1, H1, H2, (long)TT * H1, (long)H2 * H1, (long)TT * H2,
        p_b, H2, inv_np, nullptr);

    // G3: out[b,t,d] = sum_o zt[b,t,o]*w2_w[d,o] + w2_b[d] + bf16(input); 384 blocks
    gemm_nt<2, 0><<<dim3(BCNT * TT / 128, DIN / 128, 1), 256, 0, stream>>>(
        zt, w2bf, out, H2, H2, H2, DIN, 0, 0, 0, w2_b, 0, nullptr, inbf);
}

// Round 6
// 269.364 us; speedup vs baseline: 1.8459x; 1.0741x over previous
//
#include <hip/hip_runtime.h>

#define BCNT 16
#define TT 1024
#define DIN 384
#define H1 1024
#define H2 1024
#define KW 9

typedef __attribute__((ext_vector_type(8))) short bhalf8;   // 8 bf16 in 4 VGPRs
typedef __attribute__((ext_vector_type(4))) float f32x4;

typedef const __attribute__((address_space(1))) void* gas_ptr;
typedef __attribute__((address_space(3))) void* lds_ptr;

__device__ __forceinline__ float bf2f(unsigned short u) {
    return __uint_as_float(((unsigned int)u) << 16);
}
__device__ __forceinline__ unsigned short f2bf(float f) {
    unsigned int u = __float_as_uint(f);
    unsigned int r = (u + 0x7FFFu + ((u >> 16) & 1u)) >> 16;  // RNE
    return (unsigned short)r;
}
// mish(x) = x*tanh(log1p(e^x)) = x*(u^2+2u)/(u^2+2u+2), u=e^x (exact algebra)
__device__ __forceinline__ float mish_f(float x) {
    if (x > 20.f) return x;
    float u = __expf(x);
    float n = u * u + 2.f * u;
    return x * n / (n + 2.f);
}

// ---------------- prep kernels ----------------

// fused f32->bf16 cvt for input, w1_w, w2_w + zero sumsq (one launch)
__global__ __launch_bounds__(256) void k_cvt3z(
    const float* __restrict__ s0, unsigned short* __restrict__ d0, int n0,
    const float* __restrict__ s1, unsigned short* __restrict__ d1, int n1,
    const float* __restrict__ s2, unsigned short* __restrict__ d2, int n2,
    float* __restrict__ zb, int n3) {
    int i = blockIdx.x * 256 + threadIdx.x;
    const float* s; unsigned short* d; int j = i;
    if (i < n0) { s = s0; d = d0; }
    else if ((j = i - n0) < n1) { s = s1; d = d1; }
    else if ((j = i - n0 - n1) < n2) { s = s2; d = d2; }
    else if ((j = i - n0 - n1 - n2) < n3) {
        ((float4*)zb)[j] = make_float4(0.f, 0.f, 0.f, 0.f);
        return;
    } else return;
    float4 v = ((const float4*)s)[j];
    ushort4 o;
    o.x = f2bf(v.x); o.y = f2bf(v.y); o.z = f2bf(v.z); o.w = f2bf(v.w);
    ((ushort4*)d)[j] = o;
}

// per-(b,k): norm of d_w over c, then write dwn_s[b,c,k] = d_w/n * d_g * T
__global__ void k_norm_dwn(const float* __restrict__ d_w, const float* __restrict__ d_g,
                           float* __restrict__ dwn_s) {
    int idx = blockIdx.x;           // b*KW + k
    int b = idx / KW, k = idx % KW;
    float s = 0.f;
    for (int c = threadIdx.x; c < H1; c += 256) {
        float v = d_w[((size_t)b * H1 + c) * KW + k];
        s += v * v;
    }
    __shared__ float red[256];
    __shared__ float nsh;
    red[threadIdx.x] = s; __syncthreads();
    for (int st = 128; st > 0; st >>= 1) {
        if (threadIdx.x < st) red[threadIdx.x] += red[threadIdx.x + st];
        __syncthreads();
    }
    if (threadIdx.x == 0) nsh = fmaxf(sqrtf(red[0]), 1e-12f);
    __syncthreads();
    float n = nsh;
    for (int c = threadIdx.x; c < H1; c += 256) {
        size_t o = ((size_t)b * H1 + c) * KW + k;
        dwn_s[o] = d_w[o] / n * d_g[b * H1 + c] * (float)TT;
    }
}

// transpose+scale p_w AND accumulate per-(b,o) sum of squares
__global__ __launch_bounds__(256) void k_tpw2(const float* __restrict__ p_w,
                                              const float* __restrict__ p_g,
                                              unsigned short* __restrict__ pwTu,
                                              float* __restrict__ sumsq) {
    __shared__ float tile[32][33];
    __shared__ float red[8][32];
    int tx = threadIdx.x & 31, ty = threadIdx.x >> 5;  // 32 x 8
    int c0 = blockIdx.x * 32, o0 = blockIdx.y * 32, b = blockIdx.z;
    float s = 0.f;
#pragma unroll
    for (int j = 0; j < 4; j++) {
        float v = p_w[((size_t)b * H1 + c0 + ty + j * 8) * H2 + o0 + tx];
        tile[ty + j * 8][tx] = v;
        s += v * v;
    }
    red[ty][tx] = s;
    __syncthreads();
    if (ty == 0) {
        float t = 0.f;
#pragma unroll
        for (int r = 0; r < 8; r++) t += red[r][tx];
        atomicAdd(&sumsq[(size_t)b * H2 + o0 + tx], t);
    }
#pragma unroll
    for (int j = 0; j < 4; j++) {
        int o = o0 + ty + j * 8, c = c0 + tx;
        float v = tile[tx][ty + j * 8] * p_g[(size_t)b * H1 + c];
        pwTu[((size_t)b * H2 + o) * H1 + c] = f2bf(v);
    }
}

// depthwise conv along T, sliding window; 2 channels per thread (ushort2)
__global__ __launch_bounds__(256) void k_conv(const unsigned short* __restrict__ h,
                                              const float* __restrict__ dwn_s,
                                              const float* __restrict__ d_b,
                                              unsigned short* __restrict__ y) {
    int tid = threadIdx.x;
    int c2 = blockIdx.y * 256 + tid;
    int c = c2 * 2;
    int t0 = blockIdx.x * 64;
    int b = blockIdx.z;
    const ushort2* hb = (const ushort2*)(h + (size_t)b * TT * H1);
    ushort2* yb = (ushort2*)(y + (size_t)b * TT * H1);
    float k0[KW], k1[KW];
#pragma unroll
    for (int i = 0; i < KW; i++) {
        k0[i] = dwn_s[((size_t)b * H1 + c) * KW + i];
        k1[i] = dwn_s[((size_t)b * H1 + c + 1) * KW + i];
    }
    float db0 = d_b[b * H1 + c], db1 = d_b[b * H1 + c + 1];
    float w0[KW], w1[KW];
#pragma unroll
    for (int i = 0; i < 8; i++) {
        int t = t0 - 4 + i;
        if (t >= 0 && t < TT) {
            ushort2 v = hb[(size_t)t * (H1 / 2) + c2];
            w0[i] = bf2f(v.x); w1[i] = bf2f(v.y);
        } else { w0[i] = 0.f; w1[i] = 0.f; }
    }
    for (int j = 0; j < 64; j++) {
        int t = t0 + j;
        int tl = t + 4;
        if (tl < TT) {
            ushort2 v = hb[(size_t)tl * (H1 / 2) + c2];
            w0[8] = bf2f(v.x); w1[8] = bf2f(v.y);
        } else { w0[8] = 0.f; w1[8] = 0.f; }
        float a0 = db0, a1 = db1;
#pragma unroll
        for (int i = 0; i < KW; i++) { a0 += k0[i] * w0[i]; a1 += k1[i] * w1[i]; }
        ushort2 o; o.x = f2bf(a0); o.y = f2bf(a1);
        yb[(size_t)t * (H1 / 2) + c2] = o;
#pragma unroll
        for (int i = 0; i < 8; i++) { w0[i] = w0[i + 1]; w1[i] = w1[i + 1]; }
    }
}

// ------- bf16 NT MFMA GEMM: 128 x TN tile, BK=64, 256 threads, 4 blocks/CU -------
// C[m,n] = sum_k A[m,k]*B[n,k], bf16 K-contiguous. BK=64 halves barrier count vs 32.
// LDS rows 64 bf16 = 128 B. Staging chunk = 8 rows (64 lanes x 16 B); lane covers
// (row=lane>>3, slot=lane&7); slot holds global col-group slot^(row&7) [XOR swizzle,
// conflict-free on ds_read_b128: banks 4r%32 distinct, 2-way max].
// TN=128: 4 waves as 2x2, wave=64x64, acc 4x4. TN=64: wave=64x32, acc 4x2.
// MODE 0: C=bf16(mish(v + bias[n]))
// MODE 1: C=bf16(v*rsqrt(sumsq[bz*str+n]) + bias[bz*str+n])
// MODE 2: C=f32 (v + bias[n] + bf2f(residbf[idx]))
template <int MODE, int SWIZ, int TN>
__global__ __launch_bounds__(256, 4) void gemm_nt(
    const unsigned short* __restrict__ A, const unsigned short* __restrict__ Bm,
    void* __restrict__ Cp, int Kdim, int lda, int ldb, int ldc,
    long sA, long sB, long sC,
    const float* __restrict__ bias, int biasStride,
    const float* __restrict__ sumsq,
    const unsigned short* __restrict__ residbf) {
    constexpr int WN = TN / 32;                    // B frags per wave (4 or 2)
    __shared__ __attribute__((aligned(16))) unsigned short Al[128 * 64];
    __shared__ __attribute__((aligned(16))) unsigned short Bl[TN * 64];

    const int tid = threadIdx.x;
    const int lane = tid & 63, wv = tid >> 6;      // 4 waves

    int bx, by, bz;
    if constexpr (SWIZ) {
        // G2: 1024 blocks. XCD k owns batches {2k,2k+1}; m-tile fastest.
        int l = blockIdx.x;
        int xcd = l & 7, s = l >> 3;               // s: 0..127
        bz = xcd * 2 + (s >> 6);
        int u = s & 63;
        bx = u & 7; by = u >> 3;
    } else {
        bx = blockIdx.x; by = blockIdx.y; bz = blockIdx.z;
    }
    const int bm = bx * 128, bn = by * TN;

    const unsigned short* Ab = A + (size_t)sA * bz;
    const unsigned short* Bb = Bm + (size_t)sB * bz;

    // staging lane map (XOR swizzle on source column)
    const int rS = lane >> 3;                       // row within 8-row chunk
    const int cS = ((lane & 7) ^ (rS & 7)) * 8;     // global col-group offset (elems)

    const int wm = (wv >> 1) * 64, wn = (wv & 1) * (TN / 2);
    const int l16 = lane & 15, quad = lane >> 4;
    const int fx = l16 & 7;                         // read-side XOR key

    f32x4 acc[4][WN];
#pragma unroll
    for (int i = 0; i < 4; i++)
#pragma unroll
        for (int j = 0; j < WN; j++)
#pragma unroll
            for (int r = 0; r < 4; r++) acc[i][j][r] = 0.f;

    const int ktiles = Kdim / 64;
    for (int kt = 0; kt < ktiles; ++kt) {
        const int kofs = kt * 64 + cS;
        // A: 16 chunks of 8 rows, 4 per wave
#pragma unroll
        for (int i = 0; i < 4; i++) {
            const int ch = i * 4 + wv;
            const unsigned short* ga = Ab + (size_t)(bm + ch * 8 + rS) * lda + kofs;
            __builtin_amdgcn_global_load_lds((gas_ptr)ga, (lds_ptr)&Al[ch * 512], 16, 0, 0);
        }
        // B: TN/8 chunks, TN/32 per wave
#pragma unroll
        for (int i = 0; i < TN / 32; i++) {
            const int ch = i * 4 + wv;
            const unsigned short* gb = Bb + (size_t)(bn + ch * 8 + rS) * ldb + kofs;
            __builtin_amdgcn_global_load_lds((gas_ptr)gb, (lds_ptr)&Bl[ch * 512], 16, 0, 0);
        }
        __syncthreads();

#pragma unroll
        for (int kk = 0; kk < 2; kk++) {
            const int cg = ((kk * 4 + quad) ^ fx) * 8;   // swizzled col offset
            bhalf8 af[4], bf[WN];
#pragma unroll
            for (int mi = 0; mi < 4; mi++)
                af[mi] = *(const bhalf8*)&Al[(wm + mi * 16 + l16) * 64 + cg];
#pragma unroll
            for (int ni = 0; ni < WN; ni++)
                bf[ni] = *(const bhalf8*)&Bl[(wn + ni * 16 + l16) * 64 + cg];
#pragma unroll
            for (int mi = 0; mi < 4; mi++)
#pragma unroll
                for (int ni = 0; ni < WN; ni++)
                    acc[mi][ni] = __builtin_amdgcn_mfma_f32_16x16x32_bf16(af[mi], bf[ni],
                                                                         acc[mi][ni], 0, 0, 0);
        }
        __syncthreads();
    }

    // epilogue: D row = quad*4+r, col = lane&15
#pragma unroll
    for (int mi = 0; mi < 4; mi++)
#pragma unroll
        for (int ni = 0; ni < WN; ni++)
#pragma unroll
            for (int r = 0; r < 4; r++) {
                int gm = bm + wm + mi * 16 + quad * 4 + r;
                int gn = bn + wn + ni * 16 + l16;
                float v = acc[mi][ni][r];
                size_t cidx = (size_t)sC * bz + (size_t)gm * ldc + gn;
                if constexpr (MODE == 0) {
                    v = mish_f(v + bias[gn]);
                    ((unsigned short*)Cp)[cidx] = f2bf(v);
                } else if constexpr (MODE == 1) {
                    size_t si = (size_t)bz * biasStride + gn;
                    float rr = rsqrtf(fmaxf(sumsq[si], 1e-24f));
                    v = v * rr + bias[si];
                    ((unsigned short*)Cp)[cidx] = f2bf(v);
                } else {
                    v += bias[gn] + bf2f(residbf[cidx]);
                    ((float*)Cp)[cidx] = v;
                }
            }
}

// ---------------- launch ----------------

extern "C" void kernel_launch(void* const* d_in, const int* in_sizes, int n_in,
                              void* d_out, int out_size, void* d_ws, size_t ws_size,
                              hipStream_t stream) {
    const float* input = (const float*)d_in[0];
    const float* d_w   = (const float*)d_in[1];
    const float* d_g   = (const float*)d_in[2];
    const float* d_b   = (const float*)d_in[3];
    const float* p_w   = (const float*)d_in[4];
    const float* p_g   = (const float*)d_in[5];
    const float* p_b   = (const float*)d_in[6];
    const float* w1_w  = (const float*)d_in[7];
    const float* w1_b  = (const float*)d_in[8];
    const float* w2_w  = (const float*)d_in[9];
    const float* w2_b  = (const float*)d_in[10];
    float* out = (float*)d_out;

    char* ws = (char*)d_ws;
    size_t off = 0;
    auto alloc = [&](size_t bytes) {
        char* p = ws + off;
        off += (bytes + 255) & ~(size_t)255;
        return p;
    };
    float* dwn_s         = (float*)alloc((size_t)BCNT * H1 * KW * 4);
    float* sumsq         = (float*)alloc((size_t)BCNT * H2 * 4);
    unsigned short* inbf = (unsigned short*)alloc((size_t)BCNT * TT * DIN * 2);
    unsigned short* w1bf = (unsigned short*)alloc((size_t)H1 * DIN * 2);
    unsigned short* w2bf = (unsigned short*)alloc((size_t)DIN * H2 * 2);
    unsigned short* h    = (unsigned short*)alloc((size_t)BCNT * TT * H1 * 2);
    unsigned short* y    = (unsigned short*)alloc((size_t)BCNT * TT * H1 * 2);
    unsigned short* pwTu = (unsigned short*)alloc((size_t)BCNT * H2 * H1 * 2);
    unsigned short* zt   = (unsigned short*)alloc((size_t)BCNT * TT * H2 * 2);

    // f32 -> bf16 conversions + zero sumsq (one launch)
    const int n4_in = BCNT * TT * DIN / 4, n4_w1 = H1 * DIN / 4, n4_w2 = DIN * H2 / 4;
    const int n4_z = BCNT * H2 / 4;
    k_cvt3z<<<(n4_in + n4_w1 + n4_w2 + n4_z + 255) / 256, 256, 0, stream>>>(
        input, inbf, n4_in, w1_w, w1bf, n4_w1, w2_w, w2bf, n4_w2, sumsq, n4_z);

    // weight prep
    k_norm_dwn<<<BCNT * KW, 256, 0, stream>>>(d_w, d_g, dwn_s);
    k_tpw2<<<dim3(H1 / 32, H2 / 32, BCNT), 256, 0, stream>>>(p_w, p_g, pwTu, sumsq);

    // G1: h = bf16(mish(input @ w1_w^T + w1_b)), (B*T, H1); 1024 blocks, 6 K-iters
    gemm_nt<0, 0, 128><<<dim3(BCNT * TT / 128, H1 / 128, 1), 256, 0, stream>>>(
        inbf, w1bf, h, DIN, DIN, DIN, H1, 0, 0, 0, w1_b, 0, nullptr, nullptr);

    // depthwise conv -> y (B*T, H1) bf16
    k_conv<<<dim3(TT / 64, H1 / 512, BCNT), 256, 0, stream>>>(h, dwn_s, d_b, y);

    // G2 (batched, XCD-swizzled, 1024 blocks): zt = rsqrt(sumsq)*(y.pwTu) + p_b
    gemm_nt<1, 1, 128><<<dim3(1024, 1, 1), 256, 0, stream>>>(
        y, pwTu, zt, H1, H1, H1, H2, (long)TT * H1, (long)H2 * H1, (long)TT * H2,
        p_b, H2, sumsq, nullptr);

    // G3: out = zt @ w2^T + w2_b + resid; 128x64 tiles -> 768 blocks
    gemm_nt<2, 0, 64><<<dim3(BCNT * TT / 128, DIN / 64, 1), 256, 0, stream>>>(
        zt, w2bf, out, H2, H2, H2, DIN, 0, 0, 0, w2_b, 0, nullptr, inbf);
}